// Round 3
// baseline (160.445 us; speedup 1.0000x reference)
//
#include <hip/hip_runtime.h>
#include <hip/hip_bf16.h>

// Problem constants
#define B_   256
#define L_   197
#define C_   768
#define H_   48
#define NA_  10
#define ROWS (B_ * L_)            // 50432
#define OFF_SIM 38731776          // B*L*C
#define OFF_IDX 38731777

typedef __attribute__((ext_vector_type(8))) short short8;
typedef __attribute__((ext_vector_type(4))) short short4_t;
typedef __attribute__((ext_vector_type(4))) float f32x4;

static __device__ inline short f2bf(float f) {
    union { float f; unsigned u; } v; v.f = f;
    unsigned r = v.u + 0x7fffu + ((v.u >> 16) & 1u);   // round-to-nearest-even
    return (short)(r >> 16);
}

// ---------------------------------------------------------------------------
// Kw: convert ALL 10 adapters' W1 [10,48,768] and W2 [10,768,48] to bf16.
// W2 stored K-padded to 64 (zeros) so GEMM2 can use 16x16x32 mfma.
// ---------------------------------------------------------------------------
__global__ void kw_convert(const float* __restrict__ W1, const float* __restrict__ W2,
                           short* __restrict__ W1b, short* __restrict__ W2b) {
    int i = blockIdx.x * 256 + threadIdx.x;
    if (i < NA_ * H_ * C_)                     // 368640
        W1b[i] = f2bf(W1[i]);
    if (i < NA_ * C_ * 64) {                   // 491520
        int k  = i & 63;
        int nc = i >> 6;                       // a*768 + c
        W2b[i] = (k < H_) ? f2bf(W2[nc * H_ + k]) : (short)0;
    }
}

// ---------------------------------------------------------------------------
// K1a: partial sums over L. grid = B*4 blocks; each block sums ~50 rows of one b.
// partial layout [b][seg][c] f32
// ---------------------------------------------------------------------------
__global__ void k1a_partial(const float* __restrict__ x, float* __restrict__ partial) {
    int b = blockIdx.x >> 2, seg = blockIdx.x & 3;
    int l0 = seg * 50, l1 = l0 + 50; if (l1 > L_) l1 = L_;
    int t = threadIdx.x;
    const float* xb = x + (size_t)b * L_ * C_;
    float s0 = 0.f, s1 = 0.f, s2 = 0.f;
    for (int l = l0; l < l1; ++l) {
        const float* r = xb + (size_t)l * C_;
        s0 += r[t]; s1 += r[t + 256]; s2 += r[t + 512];
    }
    float* p = partial + ((size_t)b * 4 + seg) * C_;
    p[t] = s0; p[t + 256] = s1; p[t + 512] = s2;
}

// ---------------------------------------------------------------------------
// K1b: per-b mean -> sims[b][k] = dot(m,key_k)*rsqrt(max(|key_k|^2,eps))*rsqrt(max(|m|^2,eps))
// grid = B blocks of 256
// ---------------------------------------------------------------------------
__global__ void k1b_sims(const float* __restrict__ partial, const float* __restrict__ akey,
                         float* __restrict__ sims) {
    __shared__ float red[21][256];
    int b = blockIdx.x, t = threadIdx.x;
    const float* p = partial + (size_t)b * 4 * C_;
    float m[3];
    #pragma unroll
    for (int j = 0; j < 3; ++j) {
        int c = t + j * 256;
        m[j] = (p[c] + p[C_ + c] + p[2 * C_ + c] + p[3 * C_ + c]) * (1.f / (float)L_);
    }
    red[0][t] = m[0] * m[0] + m[1] * m[1] + m[2] * m[2];
    #pragma unroll
    for (int k = 0; k < NA_; ++k) {
        float kd = 0.f, kq = 0.f;
        #pragma unroll
        for (int j = 0; j < 3; ++j) {
            float kv = akey[k * C_ + t + j * 256];
            kd += m[j] * kv; kq += kv * kv;
        }
        red[1 + k][t] = kd; red[11 + k][t] = kq;
    }
    __syncthreads();
    for (int s = 128; s > 0; s >>= 1) {
        if (t < s) {
            #pragma unroll
            for (int q = 0; q < 21; ++q) red[q][t] += red[q][t + s];
        }
        __syncthreads();
    }
    if (t < NA_) {
        float msq = red[0][0];
        sims[b * NA_ + t] = red[1 + t][0] * rsqrtf(fmaxf(red[11 + t][0], 1e-12f))
                                          * rsqrtf(fmaxf(msq, 1e-12f));
    }
}

// ---------------------------------------------------------------------------
// K2: single block. per-sample argmax (ties->smallest), majority vote
// (ties->smallest), writes idx floats + reduce_sim to d_out, major to ws.
// ---------------------------------------------------------------------------
__global__ void k2_select(const float* __restrict__ sims, float* __restrict__ out,
                          int* __restrict__ majorp) {
    __shared__ int counts[NA_];
    __shared__ int majorS;
    __shared__ float rs[256];
    int t = threadIdx.x;                       // = b
    float s[NA_];
    #pragma unroll
    for (int k = 0; k < NA_; ++k) s[k] = sims[t * NA_ + k];
    int best = 0; float bv = s[0];
    #pragma unroll
    for (int k = 1; k < NA_; ++k) { if (s[k] > bv) { bv = s[k]; best = k; } }
    if (t < NA_) counts[t] = 0;
    __syncthreads();
    atomicAdd(&counts[best], 1);
    __syncthreads();
    if (t == 0) {
        int mj = 0, mc = counts[0];
        #pragma unroll
        for (int k = 1; k < NA_; ++k) { if (counts[k] > mc) { mc = counts[k]; mj = k; } }
        majorS = mj; *majorp = mj;
    }
    __syncthreads();
    int mj = majorS;
    rs[t] = s[mj];
    __syncthreads();
    for (int st = 128; st > 0; st >>= 1) { if (t < st) rs[t] += rs[t + st]; __syncthreads(); }
    if (t == 0) out[OFF_SIM] = rs[0] * (1.f / (float)B_);
    out[OFF_IDX + t] = (float)mj;
}

// ---------------------------------------------------------------------------
// K3: main fused adapter apply.  grid = ROWS/32 blocks, 128 threads (2 waves).
// Each wave owns a 16-row m-subtile. GEMM1: h = relu(x @ W1^T) via
// mfma_f32_16x16x32_bf16, A-frags from global fp32 x (converted in-reg),
// B-frags from bf16 W1. h -> LDS (bf16, padded stride 72). GEMM2: a = relu(h @
// W2^T) with K padded to 64, then bias = x + a written to out.
// ---------------------------------------------------------------------------
__launch_bounds__(128)
__global__ void k3_apply(const float* __restrict__ x, const short* __restrict__ W1b,
                         const short* __restrict__ W2b, const int* __restrict__ majorp,
                         float* __restrict__ out) {
    __shared__ short hb[32 * 72];
    const int major = *majorp;
    const short* w1 = W1b + major * (H_ * C_);
    const short* w2 = W2b + (size_t)major * (C_ * 64);

    int t = threadIdx.x;
    int w = t >> 6, l = t & 63;
    int rbase = blockIdx.x * 32 + w * 16;
    int lo16 = l & 15;
    int klane = (l >> 4) * 8;

    // zero the K-pad region [48,64) of this wave's 16 hb rows
    {
        int row = w * 16 + lo16;
        short4_t z = {0, 0, 0, 0};
        *(short4_t*)&hb[row * 72 + 48 + (l >> 4) * 4] = z;
    }

    // ---- phase 1: h[16][48] = relu(x_tile @ W1^T) ----
    f32x4 acc0 = {0,0,0,0}, acc1 = {0,0,0,0}, acc2 = {0,0,0,0};
    const float* xrow = x + (size_t)(rbase + lo16) * C_;
    for (int k0 = 0; k0 < C_; k0 += 32) {
        int kk = k0 + klane;
        float4 xa = *(const float4*)(xrow + kk);
        float4 xb = *(const float4*)(xrow + kk + 4);
        short8 af;
        af[0] = f2bf(xa.x); af[1] = f2bf(xa.y); af[2] = f2bf(xa.z); af[3] = f2bf(xa.w);
        af[4] = f2bf(xb.x); af[5] = f2bf(xb.y); af[6] = f2bf(xb.z); af[7] = f2bf(xb.w);
        short8 b0 = *(const short8*)(w1 + (0 * 16 + lo16) * C_ + kk);
        short8 b1 = *(const short8*)(w1 + (1 * 16 + lo16) * C_ + kk);
        short8 b2 = *(const short8*)(w1 + (2 * 16 + lo16) * C_ + kk);
        acc0 = __builtin_amdgcn_mfma_f32_16x16x32_bf16(af, b0, acc0, 0, 0, 0);
        acc1 = __builtin_amdgcn_mfma_f32_16x16x32_bf16(af, b1, acc1, 0, 0, 0);
        acc2 = __builtin_amdgcn_mfma_f32_16x16x32_bf16(af, b2, acc2, 0, 0, 0);
    }
    // store h tile to LDS (D layout: col = lane&15, row = (lane>>4)*4 + r)
    {
        int hrow0 = w * 16 + (l >> 4) * 4;
        #pragma unroll
        for (int r = 0; r < 4; ++r) {
            hb[(hrow0 + r) * 72 +  0 + lo16] = f2bf(fmaxf(acc0[r], 0.f));
            hb[(hrow0 + r) * 72 + 16 + lo16] = f2bf(fmaxf(acc1[r], 0.f));
            hb[(hrow0 + r) * 72 + 32 + lo16] = f2bf(fmaxf(acc2[r], 0.f));
        }
    }
    __syncthreads();

    // ---- phase 2: a = relu(h @ W2^T), bias = x + a ----
    short8 a20 = *(const short8*)&hb[(w * 16 + lo16) * 72 + klane];
    short8 a21 = *(const short8*)&hb[(w * 16 + lo16) * 72 + 32 + klane];
    int row0 = rbase + (l >> 4) * 4;
    for (int nt2 = 0; nt2 < 48; ++nt2) {
        f32x4 acc = {0,0,0,0};
        int c = nt2 * 16 + lo16;
        const short* w2n = w2 + c * 64;
        short8 b0 = *(const short8*)(w2n + klane);
        short8 b1 = *(const short8*)(w2n + 32 + klane);
        acc = __builtin_amdgcn_mfma_f32_16x16x32_bf16(a20, b0, acc, 0, 0, 0);
        acc = __builtin_amdgcn_mfma_f32_16x16x32_bf16(a21, b1, acc, 0, 0, 0);
        #pragma unroll
        for (int r = 0; r < 4; ++r) {
            size_t o = (size_t)(row0 + r) * C_ + c;
            out[o] = x[o] + fmaxf(acc[r], 0.f);
        }
    }
}

// ---------------------------------------------------------------------------
extern "C" void kernel_launch(void* const* d_in, const int* in_sizes, int n_in,
                              void* d_out, int out_size, void* d_ws, size_t ws_size,
                              hipStream_t stream) {
    const float* x    = (const float*)d_in[0];
    const float* W1   = (const float*)d_in[1];
    const float* W2   = (const float*)d_in[2];
    const float* akey = (const float*)d_in[3];
    float* out = (float*)d_out;

    char* ws = (char*)d_ws;
    short* W1b     = (short*)ws;                       //   737,280 B
    short* W2b     = (short*)(ws + 737280);            //   983,040 B
    float* partial = (float*)(ws + 1720320);           // 3,145,728 B
    float* sims    = (float*)(ws + 4866048);           //    10,240 B
    int*   majorp  = (int*)(ws + 4876288);

    hipLaunchKernelGGL(kw_convert, dim3(1920), dim3(256), 0, stream, W1, W2, W1b, W2b);
    hipLaunchKernelGGL(k1a_partial, dim3(B_ * 4), dim3(256), 0, stream, x, partial);
    hipLaunchKernelGGL(k1b_sims, dim3(B_), dim3(256), 0, stream, partial, akey, sims);
    hipLaunchKernelGGL(k2_select, dim3(1), dim3(256), 0, stream, sims, out, majorp);
    hipLaunchKernelGGL(k3_apply, dim3(ROWS / 32), dim3(128), 0, stream, x, W1b, W2b, majorp, out);
}